// Round 4
// baseline (80.128 us; speedup 1.0000x reference)
//
#include <hip/hip_runtime.h>

typedef float f4 __attribute__((ext_vector_type(4)));
typedef float f2 __attribute__((ext_vector_type(2)));

#define INV_SQRT2 0.70710678118654752440f

// Fused FrequencyLayer, round 4:
//  - 3-level Haar DWT/IDWT along S is local within blocks of 8 sequence
//    positions -> 8-point stencil per (b, h); only LayerNorm couples H.
//  - Each block now processes TWO (b, k) tiles sharing the same k
//    (b = g and b + 32): weight rows loaded once per 2 tiles, and 16 input
//    float4 loads in flight per thread (2x memory-level parallelism).
//  - LayerNorm stats for both tiles (32 values/thread) reduced with a
//    split-butterfly: live value count halves each round -> 32 shuffles
//    total (vs 192 naive). Permuted conflict-free LDS scatter, 16-lane
//    mean/rstd pass, broadcast f2 reads.
//  - R2 lesson: non-temporal hints regress on gfx950; plain loads/stores.
__device__ __forceinline__ void haar_tile(f4 (&y)[8], const f4 (&w0)[4],
                                          const f4 (&w1)[2], const f4 w2v,
                                          const f4 b2, float* vv) {
    constexpr float c = INV_SQRT2;
    #pragma unroll
    for (int hh = 0; hh < 4; ++hh) {
        float yc[8];
        #pragma unroll
        for (int j = 0; j < 8; ++j) yc[j] = y[j][hh];

        // forward Haar (3 levels), scaling folded into the details
        const float a0 = (yc[0] + yc[1]) * c;
        const float a1 = (yc[2] + yc[3]) * c;
        const float a2 = (yc[4] + yc[5]) * c;
        const float a3 = (yc[6] + yc[7]) * c;
        const float d10 = (yc[0] - yc[1]) * c * w0[0][hh];
        const float d11 = (yc[2] - yc[3]) * c * w0[1][hh];
        const float d12 = (yc[4] - yc[5]) * c * w0[2][hh];
        const float d13 = (yc[6] - yc[7]) * c * w0[3][hh];
        const float bb0 = (a0 + a1) * c;
        const float bb1 = (a2 + a3) * c;
        const float d20 = (a0 - a1) * c * w1[0][hh];
        const float d21 = (a2 - a3) * c * w1[1][hh];
        const float cc  = (bb0 + bb1) * c;
        const float d3  = (bb0 - bb1) * c * w2v[hh];

        // inverse Haar
        const float b0p = (cc + d3) * c;
        const float b1p = (cc - d3) * c;
        const float a0p = (b0p + d20) * c;
        const float a1p = (b0p - d20) * c;
        const float a2p = (b1p + d21) * c;
        const float a3p = (b1p - d21) * c;
        float lp[8];
        lp[0] = (a0p + d10) * c;
        lp[1] = (a0p - d10) * c;
        lp[2] = (a1p + d11) * c;
        lp[3] = (a1p - d11) * c;
        lp[4] = (a2p + d12) * c;
        lp[5] = (a2p - d12) * c;
        lp[6] = (a3p + d13) * c;
        lp[7] = (a3p - d13) * c;

        const float bb = b2[hh];
        #pragma unroll
        for (int j = 0; j < 8; ++j) {
            const float hpv = yc[j] - lp[j];            // high_pass
            const float v   = lp[j] + bb * hpv + yc[j]; // seq_emb + residual
            y[j][hh]   = v;                             // in-place activation
            vv[j * 2]     += v;
            vv[j * 2 + 1] += v * v;
        }
    }
}

__global__ __launch_bounds__(256) void freq_layer_fused(
    const float* __restrict__ in,        // [64, 512, 1024]
    const float* __restrict__ ww0,       // [256, 1024]
    const float* __restrict__ ww1,       // [128, 1024]
    const float* __restrict__ ww2,       // [64, 1024]
    const float* __restrict__ srt,       // [1024]
    const float* __restrict__ sqrt_beta, // [1024]
    const float* __restrict__ ln_w,      // [1024]
    const float* __restrict__ ln_b,      // [1024]
    float* __restrict__ out)             // [64, 512, 1024]
{
    constexpr int H = 1024;
    constexpr int S = 512;

    const int t  = threadIdx.x;        // 0..255
    const int k  = blockIdx.x & 63;    // s-block index (8 rows each)
    const int g  = blockIdx.x >> 6;    // 0..31 -> batches g and g+32
    const int h0 = t << 2;             // this thread's first h

    const size_t baseA = ((size_t)g * S        + (size_t)(k << 3)) * H + (size_t)h0;
    const size_t baseB = ((size_t)(g + 32) * S + (size_t)(k << 3)) * H + (size_t)h0;

    // ---- issue both tiles' input loads up front (16 outstanding x4) ----
    f4 yA[8], yB[8];
    #pragma unroll
    for (int j = 0; j < 8; ++j)
        yA[j] = *reinterpret_cast<const f4*>(in + baseA + (size_t)j * H);
    #pragma unroll
    for (int j = 0; j < 8; ++j)
        yB[j] = *reinterpret_cast<const f4*>(in + baseB + (size_t)j * H);

    // ---- per-h weights (shared by both tiles; L2-hot, same-k same-XCD) ----
    f4 s2 = *reinterpret_cast<const f4*>(srt + h0);
    s2 *= s2;                                  // srt^2
    f4 b2 = *reinterpret_cast<const f4*>(sqrt_beta + h0);
    b2 *= b2;                                  // sqrt_beta^2

    f4 w0[4], w1[2], w2v;
    #pragma unroll
    for (int j = 0; j < 4; ++j)
        w0[j] = *reinterpret_cast<const f4*>(ww0 + (size_t)((k << 2) + j) * H + h0) * s2;
    #pragma unroll
    for (int j = 0; j < 2; ++j)
        w1[j] = *reinterpret_cast<const f4*>(ww1 + (size_t)((k << 1) + j) * H + h0) * s2;
    w2v = *reinterpret_cast<const f4*>(ww2 + (size_t)k * H + h0) * s2;

    // ---- compute both tiles; stats in v[32]: i = tile*16 + row*2 + {sum,sq}
    float v[32];
    #pragma unroll
    for (int i = 0; i < 32; ++i) v[i] = 0.f;

    haar_tile(yA, w0, w1, w2v, b2, v);
    haar_tile(yB, w0, w1, w2v, b2, v + 16);

    // ---- split-butterfly wave reduction: 32 values -> 1 per lane --------
    // Round r (mask m=1<<r): live halves; lanes with (lane&m) keep the
    // upper half, others the lower. 16+8+4+2+1 shuffles, then xor-32.
    #pragma unroll
    for (int r = 0; r < 5; ++r) {
        const int m    = 1 << r;
        const int half = 16 >> r;
        const bool hi  = (t & m) != 0;
        #pragma unroll
        for (int i = 0; i < half; ++i) {
            const float send = hi ? v[i] : v[half + i];
            const float recv = __shfl_xor(send, m, 64);
            v[i] = (hi ? v[half + i] : v[i]) + recv;
        }
    }
    v[0] += __shfl_xor(v[0], 32, 64);

    // lane (within wave, low 5 bits) now holds wave-sum of value idx:
    // idx = bit-reverse5(lane&31)
    const int l5  = t & 31;
    const int idx = ((l5 & 1) << 4) | ((l5 & 2) << 2) | (l5 & 4) |
                    ((l5 & 8) >> 2) | ((l5 & 16) >> 4);

    __shared__ float red[4][32];
    __shared__ __align__(16) float stats[32];
    const int wave = t >> 6;
    if ((t & 32) == 0) red[wave][idx] = v[0];   // conflict-free permuted scatter
    __syncthreads();

    // ---- cross-wave combine + mean/rstd (16 lanes) ----------------------
    if (t < 16) {
        const float s = red[0][2 * t]     + red[1][2 * t] +
                        red[2][2 * t]     + red[3][2 * t];
        const float q = red[0][2 * t + 1] + red[1][2 * t + 1] +
                        red[2][2 * t + 1] + red[3][2 * t + 1];
        const float u   = s * (1.0f / 1024.0f);
        const float var = q * (1.0f / 1024.0f) - u * u;
        stats[2 * t]     = u;
        stats[2 * t + 1] = rsqrtf(var + 1e-12f);
    }
    __syncthreads();

    // ---- epilogue: normalize + store both tiles --------------------------
    const f4 lw = *reinterpret_cast<const f4*>(ln_w + h0);
    const f4 lb = *reinterpret_cast<const f4*>(ln_b + h0);

    #pragma unroll
    for (int j = 0; j < 8; ++j) {
        const f2 st = *reinterpret_cast<const f2*>(&stats[2 * j]);  // broadcast
        f4 o;
        #pragma unroll
        for (int hh = 0; hh < 4; ++hh)
            o[hh] = lw[hh] * ((yA[j][hh] - st[0]) * st[1]) + lb[hh];
        *reinterpret_cast<f4*>(out + baseA + (size_t)j * H) = o;
    }
    #pragma unroll
    for (int j = 0; j < 8; ++j) {
        const f2 st = *reinterpret_cast<const f2*>(&stats[16 + 2 * j]);
        f4 o;
        #pragma unroll
        for (int hh = 0; hh < 4; ++hh)
            o[hh] = lw[hh] * ((yB[j][hh] - st[0]) * st[1]) + lb[hh];
        *reinterpret_cast<f4*>(out + baseB + (size_t)j * H) = o;
    }
}

extern "C" void kernel_launch(void* const* d_in, const int* in_sizes, int n_in,
                              void* d_out, int out_size, void* d_ws, size_t ws_size,
                              hipStream_t stream) {
    const float* in   = (const float*)d_in[0];
    const float* ww0  = (const float*)d_in[1];
    const float* ww1  = (const float*)d_in[2];
    const float* ww2  = (const float*)d_in[3];
    const float* srt  = (const float*)d_in[4];
    const float* sb   = (const float*)d_in[5];
    const float* lnw  = (const float*)d_in[6];
    const float* lnb  = (const float*)d_in[7];
    float* out = (float*)d_out;

    // grid = (S/8) k-blocks x (B/2) batch-pairs = 64 * 32
    freq_layer_fused<<<dim3(64 * 32), dim3(256), 0, stream>>>(
        in, ww0, ww1, ww2, srt, sb, lnw, lnb, out);
}

// Round 5
// 46.039 us; speedup vs baseline: 1.7404x; 1.7404x over previous
//
#include <hip/hip_runtime.h>

typedef float f4 __attribute__((ext_vector_type(4)));
typedef float f2 __attribute__((ext_vector_type(2)));

#define INV_SQRT2 0.70710678118654752440f

// Fused FrequencyLayer, round 5 (= R3 base + LDS-transpose LayerNorm reduce):
//  - 3-level Haar DWT/IDWT along S is local within blocks of 8 sequence
//    positions -> 8-point stencil per (b, h); only LayerNorm couples H.
//  - Block = one (b, s-block of 8) x all H=1024. Thread t owns h=4t..4t+3.
//  - R2 lesson: non-temporal hints regress on gfx950 (47->52us).
//  - R4 lesson: divergent split-butterfly (cndmask per element) + halved
//    grid regressed 47->80us. Keep 4096 blocks, one tile per block.
//  - R5 change: LayerNorm reduce via LDS transpose instead of 96
//    shuffle+adds: 16 ds_write_b32 (2-way bank alias = free), barrier,
//    each 32-lane group strided-sums one row (16 reads) + 5-round
//    shuffle on (sum,sq). Critical path ~16+10 ops vs ~96.
__global__ __launch_bounds__(256) void freq_layer_fused(
    const float* __restrict__ in,        // [64, 512, 1024]
    const float* __restrict__ ww0,       // [256, 1024]
    const float* __restrict__ ww1,       // [128, 1024]
    const float* __restrict__ ww2,       // [64, 1024]
    const float* __restrict__ srt,       // [1024]
    const float* __restrict__ sqrt_beta, // [1024]
    const float* __restrict__ ln_w,      // [1024]
    const float* __restrict__ ln_b,      // [1024]
    float* __restrict__ out)             // [64, 512, 1024]
{
    constexpr int H = 1024;
    constexpr int S = 512;
    constexpr float c = INV_SQRT2;

    const int t  = threadIdx.x;        // 0..255
    const int k  = blockIdx.x & 63;    // s-block index (8 rows each)
    const int b  = blockIdx.x >> 6;    // batch
    const int h0 = t << 2;             // this thread's first h

    const size_t rowbase = ((size_t)b * S + (size_t)(k << 3)) * H + (size_t)h0;

    // ---- load the 8 x 4 input stencil (coalesced float4 per row) ----
    f4 y[8];
    #pragma unroll
    for (int j = 0; j < 8; ++j)
        y[j] = *reinterpret_cast<const f4*>(in + rowbase + (size_t)j * H);

    // ---- per-h weights (cached path; reused by all 4096 blocks) ----
    f4 s2 = *reinterpret_cast<const f4*>(srt + h0);
    s2 *= s2;                                  // srt^2
    f4 b2 = *reinterpret_cast<const f4*>(sqrt_beta + h0);
    b2 *= b2;                                  // sqrt_beta^2

    f4 w0[4], w1[2], w2v;
    #pragma unroll
    for (int j = 0; j < 4; ++j)
        w0[j] = *reinterpret_cast<const f4*>(ww0 + (size_t)((k << 2) + j) * H + h0) * s2;
    #pragma unroll
    for (int j = 0; j < 2; ++j)
        w1[j] = *reinterpret_cast<const f4*>(ww1 + (size_t)((k << 1) + j) * H + h0) * s2;
    w2v = *reinterpret_cast<const f4*>(ww2 + (size_t)k * H + h0) * s2;

    // ---- DWT -> scale -> IDWT -> seq_emb + residual, per h column ----
    // Activation overwritten into y[] in place; partials in v[16]:
    // v[2j] = sum of row j, v[2j+1] = sumsq of row j.
    float v[16];
    #pragma unroll
    for (int i = 0; i < 16; ++i) v[i] = 0.f;

    #pragma unroll
    for (int hh = 0; hh < 4; ++hh) {
        float yc[8];
        #pragma unroll
        for (int j = 0; j < 8; ++j) yc[j] = y[j][hh];

        // forward Haar (3 levels), with the scaling folded into the details
        const float a0 = (yc[0] + yc[1]) * c;
        const float a1 = (yc[2] + yc[3]) * c;
        const float a2 = (yc[4] + yc[5]) * c;
        const float a3 = (yc[6] + yc[7]) * c;
        const float d10 = (yc[0] - yc[1]) * c * w0[0][hh];
        const float d11 = (yc[2] - yc[3]) * c * w0[1][hh];
        const float d12 = (yc[4] - yc[5]) * c * w0[2][hh];
        const float d13 = (yc[6] - yc[7]) * c * w0[3][hh];
        const float bb0 = (a0 + a1) * c;
        const float bb1 = (a2 + a3) * c;
        const float d20 = (a0 - a1) * c * w1[0][hh];
        const float d21 = (a2 - a3) * c * w1[1][hh];
        const float cc  = (bb0 + bb1) * c;
        const float d3  = (bb0 - bb1) * c * w2v[hh];

        // inverse Haar
        const float b0p = (cc + d3) * c;
        const float b1p = (cc - d3) * c;
        const float a0p = (b0p + d20) * c;
        const float a1p = (b0p - d20) * c;
        const float a2p = (b1p + d21) * c;
        const float a3p = (b1p - d21) * c;
        float lp[8];
        lp[0] = (a0p + d10) * c;
        lp[1] = (a0p - d10) * c;
        lp[2] = (a1p + d11) * c;
        lp[3] = (a1p - d11) * c;
        lp[4] = (a2p + d12) * c;
        lp[5] = (a2p - d12) * c;
        lp[6] = (a3p + d13) * c;
        lp[7] = (a3p - d13) * c;

        const float bb = b2[hh];
        #pragma unroll
        for (int j = 0; j < 8; ++j) {
            const float hpv = yc[j] - lp[j];            // high_pass
            const float val = lp[j] + bb * hpv + yc[j]; // seq_emb + residual
            y[j][hh]  = val;                            // in-place
            v[2 * j]     += val;
            v[2 * j + 1] += val * val;
        }
    }

    // ---- LayerNorm reduce: LDS transpose + per-row 32-lane reduce -------
    __shared__ float red[16][256];              // [value][thread], 16 KB
    __shared__ __align__(8) float stats[16];    // {u, rstd} per row

    #pragma unroll
    for (int i = 0; i < 16; ++i)
        red[i][t] = v[i];                       // banks t%32, 2-way (free)
    __syncthreads();

    {
        const int g = t >> 5;                   // row 0..7 (each 32-lane group)
        const int cc2 = t & 31;
        float s = 0.f, q = 0.f;
        #pragma unroll
        for (int m = 0; m < 8; ++m) {
            s += red[2 * g][cc2 + 32 * m];      // banks cc2, 2-way (free)
            q += red[2 * g + 1][cc2 + 32 * m];
        }
        #pragma unroll
        for (int m = 1; m < 32; m <<= 1) {      // stays within 32-lane half
            s += __shfl_xor(s, m, 64);
            q += __shfl_xor(q, m, 64);
        }
        if (cc2 == 0) {
            const float u   = s * (1.0f / 1024.0f);
            const float var = q * (1.0f / 1024.0f) - u * u;
            stats[2 * g]     = u;
            stats[2 * g + 1] = rsqrtf(var + 1e-12f);
        }
    }
    __syncthreads();

    // ---- epilogue: normalize + store ------------------------------------
    const f4 lw = *reinterpret_cast<const f4*>(ln_w + h0);
    const f4 lb = *reinterpret_cast<const f4*>(ln_b + h0);

    #pragma unroll
    for (int j = 0; j < 8; ++j) {
        const f2 st = *reinterpret_cast<const f2*>(&stats[2 * j]);  // broadcast
        f4 o;
        #pragma unroll
        for (int hh = 0; hh < 4; ++hh)
            o[hh] = lw[hh] * ((y[j][hh] - st[0]) * st[1]) + lb[hh];
        *reinterpret_cast<f4*>(out + rowbase + (size_t)j * H) = o;
    }
}

extern "C" void kernel_launch(void* const* d_in, const int* in_sizes, int n_in,
                              void* d_out, int out_size, void* d_ws, size_t ws_size,
                              hipStream_t stream) {
    const float* in   = (const float*)d_in[0];
    const float* ww0  = (const float*)d_in[1];
    const float* ww1  = (const float*)d_in[2];
    const float* ww2  = (const float*)d_in[3];
    const float* srt  = (const float*)d_in[4];
    const float* sb   = (const float*)d_in[5];
    const float* lnw  = (const float*)d_in[6];
    const float* lnb  = (const float*)d_in[7];
    float* out = (float*)d_out;

    // grid = B * (S/8) = 64 * 64
    freq_layer_fused<<<dim3(64 * 64), dim3(256), 0, stream>>>(
        in, ww0, ww1, ww2, srt, sb, lnw, lnb, out);
}